// Round 11
// baseline (246.787 us; speedup 1.0000x reference)
//
#include <hip/hip_runtime.h>
#include <hip/hip_bf16.h>
#include <stdint.h>

// B=2, C=256, H=W=D=16 -> N=4096, nh=8, dh=32. ALL float32 I/O.
// Reference dead code: x_sa path (top-k, index_sample, W_out, b_out, v_sa) — epa = x_ca only.
// Round 11: conv A-operand direct global->VGPR frags (no LDS staging for A),
// B stays LDS double-buffered. LDS 48->16 KB. Everything else = round 10.

#define B_ 2
#define C_ 256
#define N_ 4096
#define NH 8
#define PADV 5832
#define CN  (C_*N_)
#define BCN (B_*CN)

typedef unsigned short u16;
typedef unsigned int   u32;

using frag16 = __attribute__((ext_vector_type(8))) short;
using f32x4  = __attribute__((ext_vector_type(4))) float;

__device__ __forceinline__ u16 f2bf(float f) {
    u32 u = __float_as_uint(f);
    u += 0x7fff + ((u >> 16) & 1);
    return (u16)(u >> 16);
}
__device__ __forceinline__ float bb(u16 h) { return __uint_as_float((u32)h << 16); }
__device__ __forceinline__ void gld16(const void* g, void* l) {
    __builtin_amdgcn_global_load_lds((const __attribute__((address_space(1))) u32*)g,
                                     (__attribute__((address_space(3))) u32*)l, 16, 0, 0);
}
__device__ __forceinline__ int padrow(int n) {
    int z = n >> 8, y = (n >> 4) & 15, x = n & 15;
    return (z + 1) * 324 + (y + 1) * 18 + (x + 1);
}

// ---- workspace (float units)
#define OFF_XB16  0            // bf16 [B][C][N] (dead after gram)
#define OFF_GP    1048576      // fp32 [8][B][256][256] gram partials (dead after nqk)
#define OFF_NQK   2097152      // bf16 [B][NH][2][32][256] (dead after soft)
#define OFF_PK    0            // bf16 [3][B][C][N] conv partials — aliases the three above
#define OFF_Y     3145728      // bf16 [B][C][N]
#define OFF_ATTB  4194304      // bf16 [B][C][N]
#define OFF_ATTP  5242880      // bf16 [B][PADV][C]
#define OFF_WT2   6735872      // bf16 [27][co][ci]
#define OFF_W2B   7620608      // bf16 [c][c'] (W_out2^T)
#define OFF_WQB   7653376      // bf16 [j][c], j<768 (Wqkvv^T)
#define OFF_XT    7751680      // bf16 [B][N][C]
#define OFF_WVT   8800256      // bf16 [c][he]
#define OFF_MT    8898560      // bf16 [B][256][256] W_eff^T rows [c''][j]
#define OFF_WFU   8964096      // bf16 [B][256][256] Wfull
#define OFF_NRM   9029632      // fp32 [B][NH][2][32]
#define OFF_RED   9030656      // fp32 [B][64][2]

// ================ merged prep ================
__global__ __launch_bounds__(256) void k_prep(const float* __restrict__ CW, const float* __restrict__ W2,
                                              const float* __restrict__ Wq, const float* __restrict__ X,
                                              u16* __restrict__ WT2, u16* __restrict__ W2B,
                                              u16* __restrict__ Wqb, u16* __restrict__ WvT,
                                              u16* __restrict__ XT, u16* __restrict__ XB,
                                              u32* __restrict__ APz, float* __restrict__ NRM) {
    __shared__ __align__(16) float ls[6912];
    float (*ts)[33] = (float(*)[33])ls;
    float (*t64)[65] = (float(*)[65])ls;
    int blk = blockIdx.x, tid = threadIdx.x;
    if (blk < 256) {                                    // WT2[t][co][ci] = conv_w[co][ci][t]
        int co = blk;
        const float* src = CW + (size_t)co * 6912;
        for (int u = tid; u < 6912; u += 256) ls[u] = src[u];
        __syncthreads();
#pragma unroll
        for (int t = 0; t < 27; ++t)
            WT2[(((size_t)t * 256 + co) << 8) + tid] = f2bf(ls[tid * 27 + t]);
    } else if (blk < 320) {                             // W2B[c][p] = W2[p][c]
        int bi = blk - 256; int c0 = (bi & 7) * 32, p0 = (bi >> 3) * 32;
        int tx = tid & 31, ty = tid >> 5;
#pragma unroll
        for (int i = 0; i < 4; ++i) ts[ty + i * 8][tx] = W2[(size_t)(p0 + ty + i * 8) * 256 + c0 + tx];
        __syncthreads();
#pragma unroll
        for (int i = 0; i < 4; ++i) W2B[(size_t)(c0 + ty + i * 8) * 256 + p0 + tx] = f2bf(ts[tx][ty + i * 8]);
    } else if (blk < 512) {                             // Wqb[j][c] = Wq[c][j], j<768
        int bi = blk - 320; int c0 = (bi & 7) * 32, j0 = (bi >> 3) * 32;
        int tx = tid & 31, ty = tid >> 5;
#pragma unroll
        for (int i = 0; i < 4; ++i) ts[ty + i * 8][tx] = Wq[(size_t)(c0 + ty + i * 8) * 1024 + j0 + tx];
        __syncthreads();
#pragma unroll
        for (int i = 0; i < 4; ++i) Wqb[(size_t)(j0 + ty + i * 8) * 256 + c0 + tx] = f2bf(ts[tx][ty + i * 8]);
    } else if (blk < 768) {                             // WvT[c][he] = Wq[c][512+he]
        int c = blk - 512;
        WvT[(size_t)c * 256 + tid] = f2bf(Wq[(size_t)c * 1024 + 512 + tid]);
    } else if (blk < 1280) {                            // XT / XB
        int idx = blk - 768;
        int n0 = (idx & 63) * 64, c0 = ((idx >> 6) & 3) * 64, b = idx >> 8;
        int tn = tid & 63, tc4 = tid >> 6;
        const float* Xb = X + (size_t)b * CN;
        u16* XBb = XB + (size_t)b * CN;
#pragma unroll
        for (int i = 0; i < 16; ++i) {
            int c = c0 + tc4 + i * 4;
            float v = Xb[(size_t)c * N_ + n0 + tn];
            t64[tc4 + i * 4][tn] = v;
            XBb[(size_t)c * N_ + n0 + tn] = f2bf(v);
        }
        __syncthreads();
        u16* Xo = XT + (size_t)b * N_ * C_;
#pragma unroll
        for (int i = 0; i < 16; ++i)
            Xo[(size_t)(n0 + tc4 + i * 4) * C_ + c0 + tn] = f2bf(t64[tn][tc4 + i * 4]);
    } else if (blk < 7112) {                            // zero ATTp
        APz[(size_t)(blk - 1280) * 256 + tid] = 0;
    } else {                                            // zero NRM (1024 fp32)
        ((float4*)NRM)[tid] = make_float4(0.f, 0.f, 0.f, 0.f);
    }
}

// ================ Gram partials: GP[s][b][c][c'] = sum_{n in slice s} x[c][n] x[c'][n] ================
__global__ __launch_bounds__(256) void k_gram(const u16* __restrict__ XB, float* __restrict__ GP) {
    __shared__ __align__(16) u16 As[2][8192], Bs[2][8192];
    int mt = blockIdx.x & 1, nt = blockIdx.x >> 1, s = blockIdx.y, b = blockIdx.z;
    int c0 = mt * 128, c0p = nt * 128, k0 = s * 512;
    int tid = threadIdx.x, lane = tid & 63, w = tid >> 6;
    int wm = w & 1, wn = w >> 1, qm = lane >> 4, lm = lane & 15;
    int srow = lane >> 3;
    int sperm = (((lane & 7) ^ srow) << 3);
    const u16* aB = XB + ((size_t)(b * 256 + c0 + w * 32 + srow)) * 4096 + k0 + sperm;
    const u16* bB = XB + ((size_t)(b * 256 + c0p + w * 32 + srow)) * 4096 + k0 + sperm;
    int rdp = ((lm & 7) << 3);
    f32x4 acc[4][4] = {};
    auto stg = [&](int p, int kt) {
#pragma unroll
        for (int i = 0; i < 4; ++i) {
            gld16(aB + (size_t)i * 32768 + kt * 64, &As[p][w * 2048 + i * 512]);
            gld16(bB + (size_t)i * 32768 + kt * 64, &Bs[p][w * 2048 + i * 512]);
        }
    };
    stg(0, 0);
#pragma unroll
    for (int kt = 0; kt < 8; ++kt) {
        int p = kt & 1;
        __syncthreads();
        if (kt < 7) stg(p ^ 1, kt + 1);
#pragma unroll
        for (int c2 = 0; c2 < 2; ++c2) {
            frag16 af[4], bf[4];
#pragma unroll
            for (int i = 0; i < 4; ++i)
                af[i] = *(const frag16*)&As[p][(wm * 64 + i * 16 + lm) * 64 + ((((c2 * 4 + qm) << 3) ^ rdp))];
#pragma unroll
            for (int j = 0; j < 4; ++j)
                bf[j] = *(const frag16*)&Bs[p][(wn * 64 + j * 16 + lm) * 64 + ((((c2 * 4 + qm) << 3) ^ rdp))];
#pragma unroll
            for (int i = 0; i < 4; ++i)
#pragma unroll
                for (int j = 0; j < 4; ++j)
                    acc[i][j] = __builtin_amdgcn_mfma_f32_16x16x32_bf16(af[i], bf[j], acc[i][j], 0, 0, 0);
        }
    }
    float* o = GP + (((size_t)s * B_ + b) * 256 + c0 + wm * 64) * 256 + c0p + wn * 64;
#pragma unroll
    for (int i = 0; i < 4; ++i)
#pragma unroll
        for (int j = 0; j < 4; ++j)
#pragma unroll
            for (int r = 0; r < 4; ++r)
                o[(size_t)(i * 16 + qm * 4 + r) * 256 + j * 16 + lm] = acc[i][j][r];
}

// ================ NQ/NK + norm partials ================
__global__ __launch_bounds__(256) void k_nqk(const float* __restrict__ GP, const u16* __restrict__ Wqb,
                                             u16* __restrict__ NQK, float* __restrict__ NRM) {
    __shared__ float Gs[16][260];
    int ct = blockIdx.x, h = blockIdx.y, b = blockIdx.z, t = threadIdx.x;
#pragma unroll
    for (int i = 0; i < 16; ++i) {
        float v = 0.f;
#pragma unroll
        for (int s = 0; s < 8; ++s)
            v += GP[(((size_t)s * B_ + b) * 256 + ct * 16 + i) * 256 + t];
        Gs[i][t] = v;
    }
    __syncthreads();
    int o = t >> 3, cg = t & 7;
    int cl0 = cg * 2, cl1 = cg * 2 + 1;
    const u16* Wk = Wqb + (size_t)(256 + h * 32 + o) * 256;
    const u16* Wqr = Wqb + (size_t)(h * 32 + o) * 256;
    float ak0 = 0.f, ak1 = 0.f, aq0 = 0.f, aq1 = 0.f;
    for (int cp = 0; cp < 256; cp += 8) {
        uint4 kv = *(const uint4*)(Wk + cp);
        uint4 qv = *(const uint4*)(Wqr + cp);
        const u16 *kh = (const u16*)&kv, *qh = (const u16*)&qv;
#pragma unroll
        for (int j = 0; j < 8; ++j) {
            float kf = bb(kh[j]), qf = bb(qh[j]);
            float g0 = Gs[cl0][cp + j], g1v = Gs[cl1][cp + j];
            ak0 += kf * g0; ak1 += kf * g1v;
            aq0 += qf * g0; aq1 += qf * g1v;
        }
    }
    size_t base_q = (((size_t)(b * NH + h) * 2 + 0) * 32 + o) * 256 + ct * 16 + cg * 2;
    *(u32*)(NQK + base_q)        = (u32)f2bf(aq0) | ((u32)f2bf(aq1) << 16);
    *(u32*)(NQK + base_q + 8192) = (u32)f2bf(ak0) | ((u32)f2bf(ak1) << 16);
    u32 wq = *(const u32*)(Wqr + ct * 16 + cg * 2);
    u32 wk = *(const u32*)(Wk + ct * 16 + cg * 2);
    float pq = bb((u16)wq) * aq0 + bb((u16)(wq >> 16)) * aq1;
    float pk = bb((u16)wk) * ak0 + bb((u16)(wk >> 16)) * ak1;
    pq += __shfl_xor(pq, 1); pq += __shfl_xor(pq, 2); pq += __shfl_xor(pq, 4);
    pk += __shfl_xor(pk, 1); pk += __shfl_xor(pk, 2); pk += __shfl_xor(pk, 4);
    if (cg == 0) {
        atomicAdd(&NRM[b * 512 + h * 64 + o], pq);
        atomicAdd(&NRM[b * 512 + h * 64 + 32 + o], pk);
    }
}

// ================ scores (MFMA) + softmax + W_eff strip ================
__global__ __launch_bounds__(256) void k_soft(const u16* __restrict__ NQK, const u16* __restrict__ Wqb,
                                              const u16* __restrict__ WvT, const float* __restrict__ NRM,
                                              u16* __restrict__ MT) {
    __shared__ __align__(16) u16 Ws[8192], Ns[8192];
    __shared__ float Sm[32][33];
    __shared__ float Ab[32][33];
    __shared__ float iqS[32], ikS[32];
    int h = blockIdx.x, b = blockIdx.y;
    int tid = threadIdx.x, lane = tid & 63, w = tid >> 6;
    int wm = w & 1, wn = w >> 1, qm = lane >> 4, lm = lane & 15;
    const u16* Wq = Wqb + ((size_t)h * 32) * 256;
    const u16* NK = NQK + (((size_t)(b * NH + h) * 2 + 1) * 32) * 256;
#pragma unroll
    for (int rp = 0; rp < 4; ++rp) {
        int row = rp * 8 + w * 2 + (lane >> 5);
        int cg = (lane & 31) ^ (row & 31);
        gld16(Wq + (size_t)row * 256 + cg * 8, &Ws[rp * 2048 + w * 512]);
        gld16(NK + (size_t)row * 256 + cg * 8, &Ns[rp * 2048 + w * 512]);
    }
    if (tid < 32) {
        iqS[tid] = 1.0f / fmaxf(sqrtf(fmaxf(NRM[b * 512 + h * 64 + tid], 0.f)), 1e-12f);
        ikS[tid] = 1.0f / fmaxf(sqrtf(fmaxf(NRM[b * 512 + h * 64 + 32 + tid], 0.f)), 1e-12f);
    }
    __syncthreads();
    f32x4 acc = {};
    int rowA = wm * 16 + lm, rowB = wn * 16 + lm;
#pragma unroll
    for (int kk = 0; kk < 8; ++kk) {
        int sA = ((kk * 4 + qm) ^ (rowA & 31)) << 3;
        int sB = ((kk * 4 + qm) ^ (rowB & 31)) << 3;
        frag16 af = *(const frag16*)&Ws[rowA * 256 + sA];
        frag16 bf = *(const frag16*)&Ns[rowB * 256 + sB];
        acc = __builtin_amdgcn_mfma_f32_16x16x32_bf16(af, bf, acc, 0, 0, 0);
    }
#pragma unroll
    for (int r = 0; r < 4; ++r) Sm[wm * 16 + qm * 4 + r][wn * 16 + lm] = acc[r];
    __syncthreads();
    if (tid < 32) {
        float iq = iqS[tid];
        float sv[32], m = -1e30f;
#pragma unroll
        for (int e = 0; e < 32; ++e) { sv[e] = Sm[tid][e] * iq * ikS[e]; m = fmaxf(m, sv[e]); }
        float sm = 0.f;
#pragma unroll
        for (int e = 0; e < 32; ++e) { sv[e] = __expf(sv[e] - m); sm += sv[e]; }
        float rin = 1.0f / sm;
#pragma unroll
        for (int e = 0; e < 32; ++e) Ab[tid][e] = sv[e] * rin;
    }
    __syncthreads();
    frag16 bf2[2];
#pragma unroll
    for (int j = 0; j < 2; ++j) {
        __align__(16) u16 tmp[8];
#pragma unroll
        for (int ii = 0; ii < 8; ++ii) tmp[ii] = f2bf(Ab[j * 16 + lm][qm * 8 + ii]);
        bf2[j] = *(const frag16*)tmp;
    }
    f32x4 acc2[4][2] = {};
#pragma unroll
    for (int i = 0; i < 4; ++i) {
        int row = w * 64 + i * 16 + lm;
        frag16 af = *(const frag16*)&WvT[(size_t)row * 256 + h * 32 + qm * 8];
#pragma unroll
        for (int j = 0; j < 2; ++j)
            acc2[i][j] = __builtin_amdgcn_mfma_f32_16x16x32_bf16(af, bf2[j], acc2[i][j], 0, 0, 0);
    }
    u16* Mo = MT + (size_t)b * 65536;
#pragma unroll
    for (int i = 0; i < 4; ++i)
#pragma unroll
        for (int j = 0; j < 2; ++j)
#pragma unroll
            for (int r = 0; r < 4; ++r)
                Mo[(size_t)(w * 64 + i * 16 + qm * 4 + r) * 256 + h * 32 + j * 16 + lm] = f2bf(acc2[i][j][r]);
}

// ================ Wfull[c][c''] = g1[c] * sum_j W2B[c][j] * MT[c''][j] ================
__global__ __launch_bounds__(256) void k_wfull(const u16* __restrict__ W2B, const u16* __restrict__ MT,
                                               const float* __restrict__ g1, u16* __restrict__ WFU) {
    __shared__ __align__(16) u16 As[2][8192], Bs[2][8192];
    int c0 = blockIdx.x * 128, cq0 = blockIdx.y * 128, b = blockIdx.z;
    int tid = threadIdx.x, lane = tid & 63, w = tid >> 6;
    int wm = w & 1, wn = w >> 1, qm = lane >> 4, lm = lane & 15;
    int srow = lane >> 3;
    int sperm = (((lane & 7) ^ srow) << 3);
    const u16* aB = W2B + ((size_t)(c0 + w * 32 + srow)) * 256 + sperm;
    const u16* bB = MT + ((size_t)(b * 256 + cq0 + w * 32 + srow)) * 256 + sperm;
    int rdp = ((lm & 7) << 3);
    f32x4 acc[4][4] = {};
    auto stg = [&](int p, int kc) {
#pragma unroll
        for (int i = 0; i < 4; ++i) {
            gld16(aB + i * 2048 + kc * 64, &As[p][w * 2048 + i * 512]);
            gld16(bB + i * 2048 + kc * 64, &Bs[p][w * 2048 + i * 512]);
        }
    };
    stg(0, 0);
#pragma unroll
    for (int kt = 0; kt < 4; ++kt) {
        int p = kt & 1;
        __syncthreads();
        if (kt < 3) stg(p ^ 1, kt + 1);
#pragma unroll
        for (int c2 = 0; c2 < 2; ++c2) {
            frag16 af[4], bf[4];
#pragma unroll
            for (int i = 0; i < 4; ++i)
                af[i] = *(const frag16*)&As[p][(wm * 64 + i * 16 + lm) * 64 + ((((c2 * 4 + qm) << 3) ^ rdp))];
#pragma unroll
            for (int j = 0; j < 4; ++j)
                bf[j] = *(const frag16*)&Bs[p][(wn * 64 + j * 16 + lm) * 64 + ((((c2 * 4 + qm) << 3) ^ rdp))];
#pragma unroll
            for (int i = 0; i < 4; ++i)
#pragma unroll
                for (int j = 0; j < 4; ++j)
                    acc[i][j] = __builtin_amdgcn_mfma_f32_16x16x32_bf16(af[i], bf[j], acc[i][j], 0, 0, 0);
        }
    }
#pragma unroll
    for (int i = 0; i < 4; ++i)
#pragma unroll
        for (int r = 0; r < 4; ++r) {
            int c = c0 + wm * 64 + i * 16 + qm * 4 + r;
            float gv = g1[c];
#pragma unroll
            for (int j = 0; j < 4; ++j) {
                int cc = cq0 + wn * 64 + j * 16 + lm;
                WFU[((size_t)b * 256 + c) * 256 + cc] = f2bf(gv * acc[i][j][r]);
            }
        }
}

// ================ fused attention GEMM: ATT = x + Wfull @ x + g1*b2 -> ATTb, ATTp ================
__global__ __launch_bounds__(256) void k_att(const u16* __restrict__ WFU, const u16* __restrict__ XT,
                                             const float* __restrict__ bias2, const float* __restrict__ g1,
                                             const float* __restrict__ X, u16* __restrict__ ATTb,
                                             u16* __restrict__ ATTp) {
    __shared__ __align__(16) u16 As[2][8192], Bs[2][8192];
    int n0 = blockIdx.x * 128, c0 = blockIdx.y * 128, b = blockIdx.z;
    int tid = threadIdx.x, lane = tid & 63, w = tid >> 6;
    int wm = w & 1, wn = w >> 1, qm = lane >> 4, lm = lane & 15;
    int srow = lane >> 3;
    int sperm = (((lane & 7) ^ srow) << 3);
    const u16* aB = WFU + ((size_t)(b * 256 + c0 + w * 32 + srow)) * 256 + sperm;
    const u16* bB = XT + ((size_t)(b * N_ + n0 + w * 32 + srow)) * 256 + sperm;
    int rdp = ((lm & 7) << 3);
    f32x4 acc[4][4] = {};
    auto stg = [&](int p, int kc) {
#pragma unroll
        for (int i = 0; i < 4; ++i) {
            gld16(aB + i * 2048 + kc * 64, &As[p][w * 2048 + i * 512]);
            gld16(bB + i * 2048 + kc * 64, &Bs[p][w * 2048 + i * 512]);
        }
    };
    stg(0, 0);
#pragma unroll
    for (int kt = 0; kt < 4; ++kt) {
        int p = kt & 1;
        __syncthreads();
        if (kt < 3) stg(p ^ 1, kt + 1);
#pragma unroll
        for (int c2 = 0; c2 < 2; ++c2) {
            frag16 af[4], bf[4];
#pragma unroll
            for (int i = 0; i < 4; ++i)
                af[i] = *(const frag16*)&As[p][(wm * 64 + i * 16 + lm) * 64 + ((((c2 * 4 + qm) << 3) ^ rdp))];
#pragma unroll
            for (int j = 0; j < 4; ++j)
                bf[j] = *(const frag16*)&Bs[p][(wn * 64 + j * 16 + lm) * 64 + ((((c2 * 4 + qm) << 3) ^ rdp))];
#pragma unroll
            for (int i = 0; i < 4; ++i)
#pragma unroll
                for (int j = 0; j < 4; ++j)
                    acc[i][j] = __builtin_amdgcn_mfma_f32_16x16x32_bf16(af[i], bf[j], acc[i][j], 0, 0, 0);
        }
    }
    int c_base = c0 + wm * 64, n_base = n0 + wn * 64;
    const float* xin = X + (size_t)b * CN;
    u16* Ao = ATTb + (size_t)b * CN;
    u16* Ap = ATTp + ((size_t)b * PADV << 8);
    float val[4][4][4];
#pragma unroll
    for (int i = 0; i < 4; ++i)
#pragma unroll
        for (int r = 0; r < 4; ++r) {
            int c = c_base + i * 16 + qm * 4 + r;
            float gb2 = g1[c] * bias2[c];
#pragma unroll
            for (int j = 0; j < 4; ++j) {
                int n = n_base + j * 16 + lm;
                float v = xin[(size_t)c * N_ + n] + acc[i][j][r] + gb2;
                val[i][j][r] = v;
                Ao[(size_t)c * N_ + n] = f2bf(v);
            }
        }
#pragma unroll
    for (int j = 0; j < 4; ++j) {
        int n = n_base + j * 16 + lm;
        int pr = padrow(n);
#pragma unroll
        for (int i = 0; i < 4; ++i) {
            ushort4 pk;
            pk.x = f2bf(val[i][j][0]); pk.y = f2bf(val[i][j][1]);
            pk.z = f2bf(val[i][j][2]); pk.w = f2bf(val[i][j][3]);
            *(ushort4*)&Ap[((size_t)pr << 8) + c_base + i * 16 + qm * 4] = pk;
        }
    }
}

// ================ conv 3^3 MFMA: A direct global->reg frags, B via LDS dbuf ================
__global__ __launch_bounds__(256) void k_conv_mfma(const u16* __restrict__ WT2, const u16* __restrict__ ATTp,
                                                   u16* __restrict__ Pk) {
    __shared__ __align__(16) u16 Bs[2][4096];
    int n0 = blockIdx.x * 64;
    int co0 = (blockIdx.y & 1) * 128, ks = blockIdx.y >> 1;
    int b = blockIdx.z;
    int tid = threadIdx.x, lane = tid & 63, w = tid >> 6;
    int wm = w & 1, wn = w >> 1, qm = lane >> 4, lm = lane & 15;
    int srow = lane >> 3;
    int sperm = (((lane & 7) ^ srow) << 3);
    const u16* aRow[4];                                 // per-lane A row pointers (16B frags inline)
#pragma unroll
    for (int i = 0; i < 4; ++i)
        aRow[i] = WT2 + (((size_t)ks * 9 * 256 + co0 + wm * 64 + i * 16 + lm) << 8);
    int prA[2];
#pragma unroll
    for (int i = 0; i < 2; ++i) prA[i] = padrow(n0 + w * 16 + i * 8 + srow) << 8;
    const u16* bB = ATTp + ((size_t)b * PADV << 8) + ((ks - 1) * 324 << 8) + sperm;
    int rdp = ((lm & 7) << 3);
    f32x4 acc[4][2] = {};
    auto stgB = [&](int p, int kt) {
        int tap9 = kt >> 2, kc = kt & 3;
        int K9 = ((tap9 / 3) - 1) * 18 + (tap9 % 3 - 1);   // constant-folds under full unroll
#pragma unroll
        for (int i = 0; i < 2; ++i)
            gld16(bB + prA[i] + K9 * 256 + kc * 64, &Bs[p][w * 1024 + i * 512]);
    };
    auto ldA = [&](int kt, int c2, frag16* af) {
        int tap9 = kt >> 2, kc = kt & 3;
        size_t off = ((size_t)tap9 << 16) + kc * 64 + (c2 * 4 + qm) * 8;
#pragma unroll
        for (int i = 0; i < 4; ++i) af[i] = *(const frag16*)(aRow[i] + off);
    };
    stgB(0, 0);
    frag16 afc[4];
    ldA(0, 0, afc);
#pragma unroll
    for (int kt = 0; kt < 36; ++kt) {
        int p = kt & 1;
        __syncthreads();
        if (kt < 35) stgB(p ^ 1, kt + 1);
#pragma unroll
        for (int c2 = 0; c2 < 2; ++c2) {
            frag16 afn[4];
            if (c2 == 0) ldA(kt, 1, afn);
            else ldA(kt < 35 ? kt + 1 : kt, 0, afn);    // prefetch next chunk's A frags
            frag16 bf[2];
#pragma unroll
            for (int j = 0; j < 2; ++j)
                bf[j] = *(const frag16*)&Bs[p][(wn * 32 + j * 16 + lm) * 64 + ((((c2 * 4 + qm) << 3) ^ rdp))];
#pragma unroll
            for (int i = 0; i < 4; ++i)
#pragma unroll
                for (int j = 0; j < 2; ++j)
                    acc[i][j] = __builtin_amdgcn_mfma_f32_16x16x32_bf16(afc[i], bf[j], acc[i][j], 0, 0, 0);
#pragma unroll
            for (int i = 0; i < 4; ++i) afc[i] = afn[i];
        }
    }
    u16* Pb = Pk + ((size_t)(ks * B_ + b) * C_ + co0 + wm * 64) * N_ + n0 + wn * 32;
#pragma unroll
    for (int i = 0; i < 4; ++i)
#pragma unroll
        for (int j = 0; j < 2; ++j)
#pragma unroll
            for (int r = 0; r < 4; ++r)
                Pb[(size_t)(i * 16 + qm * 4 + r) * N_ + j * 16 + lm] = f2bf(acc[i][j][r]);
}

// ================ combine bf16 split-K -> bf16 Y + batch mean/var partials ================
__global__ __launch_bounds__(256) void k_gn_reduce(const u16* __restrict__ Pk, u16* __restrict__ Y,
                                                   float* __restrict__ RED) {
    int blk = blockIdx.x, b = blockIdx.y;
    size_t base = (size_t)b * CN + (size_t)blk * 16384;
    const u16* p0 = Pk + base;
    const u16* p1 = Pk + BCN + base;
    const u16* p2 = Pk + (size_t)2 * BCN + base;
    u16* y = Y + base;
    float s = 0.f, q = 0.f;
    for (int u = threadIdx.x * 8; u < 16384; u += 2048) {
        uint4 a = *(const uint4*)&p0[u];
        uint4 c1 = *(const uint4*)&p1[u];
        uint4 c2 = *(const uint4*)&p2[u];
        const u16 *A = (const u16*)&a, *B1 = (const u16*)&c1, *C2 = (const u16*)&c2;
        __align__(16) u16 outp[8];
#pragma unroll
        for (int i = 0; i < 8; ++i) {
            float v = bb(A[i]) + bb(B1[i]) + bb(C2[i]);
            s += v; q += v * v;
            outp[i] = f2bf(v);
        }
        *(uint4*)&y[u] = *(const uint4*)outp;
    }
#pragma unroll
    for (int off = 32; off; off >>= 1) { s += __shfl_down(s, off); q += __shfl_down(q, off); }
    __shared__ float rs_[4], rq[4];
    int lane = threadIdx.x & 63, wv = threadIdx.x >> 6;
    if (!lane) { rs_[wv] = s; rq[wv] = q; }
    __syncthreads();
    if (threadIdx.x == 0) {
        RED[((size_t)b * 64 + blk) * 2 + 0] = rs_[0] + rs_[1] + rs_[2] + rs_[3];
        RED[((size_t)b * 64 + blk) * 2 + 1] = rq[0] + rq[1] + rq[2] + rq[3];
    }
}

// ================ finalize ================
__global__ __launch_bounds__(256) void k_final(const u16* __restrict__ Y, const u16* __restrict__ ATTb,
                                               const float* __restrict__ RED, const float* __restrict__ gw,
                                               const float* __restrict__ gb, float* __restrict__ out) {
    int i = blockIdx.x * 256 + threadIdx.x;
    int b = i >> 20;
    int c = (i >> 12) & 255;
    __shared__ float smu[2];
    if (threadIdx.x < 64) {
        float s = RED[((size_t)b * 64 + threadIdx.x) * 2 + 0];
        float q = RED[((size_t)b * 64 + threadIdx.x) * 2 + 1];
#pragma unroll
        for (int off = 32; off; off >>= 1) { s += __shfl_down(s, off); q += __shfl_down(q, off); }
        if (threadIdx.x == 0) {
            float inv = 1.0f / (float)CN;
            float mu = s * inv, var = q * inv - mu * mu;
            smu[0] = mu; smu[1] = rsqrtf(var + 1e-5f);
        }
    }
    __syncthreads();
    float v = (bb(Y[i]) - smu[0]) * smu[1] * gw[c] + gb[c] + bb(ATTb[i]);
    out[i] = v >= 0.f ? v : 0.01f * v;
}

extern "C" void kernel_launch(void* const* d_in, const int* in_sizes, int n_in,
                              void* d_out, int out_size, void* d_ws, size_t ws_size,
                              hipStream_t stream) {
    const float* x      = (const float*)d_in[0];
    const float* Wqkvv  = (const float*)d_in[1];
    // d_in[2] W_out, d_in[3] b_out, d_in[10] index_sample: DEAD in reference
    const float* W_out2 = (const float*)d_in[4];
    const float* b_out2 = (const float*)d_in[5];
    const float* gamma1 = (const float*)d_in[6];
    const float* conv_w = (const float*)d_in[7];
    const float* gn_w   = (const float*)d_in[8];
    const float* gn_b   = (const float*)d_in[9];
    float* out = (float*)d_out;
    float* ws = (float*)d_ws;

    u16*   XB   = (u16*)(ws + OFF_XB16);
    float* GP   = ws + OFF_GP;
    u16*   NQK  = (u16*)(ws + OFF_NQK);
    u16*   Pk   = (u16*)(ws + OFF_PK);    // aliases XB/GP/NQK (all dead before conv)
    u16*   Y    = (u16*)(ws + OFF_Y);
    u16*   ATTb = (u16*)(ws + OFF_ATTB);
    u16*   ATTp = (u16*)(ws + OFF_ATTP);
    u16*   WT2  = (u16*)(ws + OFF_WT2);
    u16*   W2B  = (u16*)(ws + OFF_W2B);
    u16*   Wqb  = (u16*)(ws + OFF_WQB);
    u16*   XT   = (u16*)(ws + OFF_XT);
    u16*   WvT  = (u16*)(ws + OFF_WVT);
    u16*   MT   = (u16*)(ws + OFF_MT);
    u16*   WFU  = (u16*)(ws + OFF_WFU);
    float* NRM  = ws + OFF_NRM;
    float* RED  = ws + OFF_RED;

    k_prep      <<<7113, 256, 0, stream>>>(conv_w, W_out2, Wqkvv, x, WT2, W2B, Wqb, WvT, XT, XB, (u32*)ATTp, NRM);
    k_gram      <<<dim3(4, 8, B_), 256, 0, stream>>>(XB, GP);
    k_nqk       <<<dim3(16, NH, B_), 256, 0, stream>>>(GP, Wqb, NQK, NRM);
    k_soft      <<<dim3(NH, B_), 256, 0, stream>>>(NQK, Wqb, WvT, NRM, MT);
    k_wfull     <<<dim3(2, 2, B_), 256, 0, stream>>>(W2B, MT, gamma1, WFU);
    k_att       <<<dim3(32, 2, B_), 256, 0, stream>>>(WFU, XT, b_out2, gamma1, x, ATTb, ATTp);
    k_conv_mfma <<<dim3(64, 6, B_), 256, 0, stream>>>(WT2, ATTp, Pk);
    k_gn_reduce <<<dim3(64, B_), 256, 0, stream>>>(Pk, Y, RED);
    k_final     <<<8192, 256, 0, stream>>>(Y, ATTb, RED, gn_w, gn_b, out);
}

// Round 12
// 178.721 us; speedup vs baseline: 1.3809x; 1.3809x over previous
//
#include <hip/hip_runtime.h>
#include <hip/hip_bf16.h>
#include <stdint.h>

// B=2, C=256, H=W=D=16 -> N=4096, nh=8, dh=32. ALL float32 I/O.
// Reference dead code: x_sa path (top-k, index_sample, W_out, b_out, v_sa) — epa = x_ca only.
// Round 12: conv reverted to r10 (direct-A regression: shared vmcnt FIFO collapsed
// the B pipeline). gram 16 k-slices (128 blocks), att retiled 128cx64n (256 blocks).

#define B_ 2
#define C_ 256
#define N_ 4096
#define NH 8
#define PADV 5832
#define CN  (C_*N_)
#define BCN (B_*CN)

typedef unsigned short u16;
typedef unsigned int   u32;

using frag16 = __attribute__((ext_vector_type(8))) short;
using f32x4  = __attribute__((ext_vector_type(4))) float;

__device__ __forceinline__ u16 f2bf(float f) {
    u32 u = __float_as_uint(f);
    u += 0x7fff + ((u >> 16) & 1);
    return (u16)(u >> 16);
}
__device__ __forceinline__ float bb(u16 h) { return __uint_as_float((u32)h << 16); }
__device__ __forceinline__ void gld16(const void* g, void* l) {
    __builtin_amdgcn_global_load_lds((const __attribute__((address_space(1))) u32*)g,
                                     (__attribute__((address_space(3))) u32*)l, 16, 0, 0);
}
__device__ __forceinline__ int padrow(int n) {
    int z = n >> 8, y = (n >> 4) & 15, x = n & 15;
    return (z + 1) * 324 + (y + 1) * 18 + (x + 1);
}

// ---- workspace (float units), ~35.9 MB
#define OFF_XB16  0            // bf16 [B][C][N] (dead after gram)
#define OFF_GP    1048576      // fp32 [16][B][256][256] gram partials (dead after nqk)
#define OFF_PK    0            // bf16 [3][B][C][N] conv partials — aliases XB+GP exactly
#define OFF_NQK   3145728      // bf16 [B][NH][2][32][256] (dead after soft; Y aliases)
#define OFF_Y     3145728      // bf16 [B][C][N]
#define OFF_ATTB  4194304      // bf16 [B][C][N]
#define OFF_ATTP  5242880      // bf16 [B][PADV][C]
#define OFF_WT2   6735872      // bf16 [27][co][ci]
#define OFF_W2B   7620608      // bf16 [c][c'] (W_out2^T)
#define OFF_WQB   7653376      // bf16 [j][c], j<768 (Wqkvv^T)
#define OFF_XT    7751680      // bf16 [B][N][C]
#define OFF_WVT   8800256      // bf16 [c][he]
#define OFF_MT    8833024      // bf16 [B][256][256] W_eff^T rows [c''][j]
#define OFF_WFU   8898560      // bf16 [B][256][256] Wfull
#define OFF_NRM   8964096      // fp32 [B][NH][2][32]
#define OFF_RED   8965120      // fp32 [B][64][2]

// ================ merged prep ================
__global__ __launch_bounds__(256) void k_prep(const float* __restrict__ CW, const float* __restrict__ W2,
                                              const float* __restrict__ Wq, const float* __restrict__ X,
                                              u16* __restrict__ WT2, u16* __restrict__ W2B,
                                              u16* __restrict__ Wqb, u16* __restrict__ WvT,
                                              u16* __restrict__ XT, u16* __restrict__ XB,
                                              u32* __restrict__ APz, float* __restrict__ NRM) {
    __shared__ __align__(16) float ls[6912];
    float (*ts)[33] = (float(*)[33])ls;
    float (*t64)[65] = (float(*)[65])ls;
    int blk = blockIdx.x, tid = threadIdx.x;
    if (blk < 256) {                                    // WT2[t][co][ci] = conv_w[co][ci][t]
        int co = blk;
        const float* src = CW + (size_t)co * 6912;
        for (int u = tid; u < 6912; u += 256) ls[u] = src[u];
        __syncthreads();
#pragma unroll
        for (int t = 0; t < 27; ++t)
            WT2[(((size_t)t * 256 + co) << 8) + tid] = f2bf(ls[tid * 27 + t]);
    } else if (blk < 320) {                             // W2B[c][p] = W2[p][c]
        int bi = blk - 256; int c0 = (bi & 7) * 32, p0 = (bi >> 3) * 32;
        int tx = tid & 31, ty = tid >> 5;
#pragma unroll
        for (int i = 0; i < 4; ++i) ts[ty + i * 8][tx] = W2[(size_t)(p0 + ty + i * 8) * 256 + c0 + tx];
        __syncthreads();
#pragma unroll
        for (int i = 0; i < 4; ++i) W2B[(size_t)(c0 + ty + i * 8) * 256 + p0 + tx] = f2bf(ts[tx][ty + i * 8]);
    } else if (blk < 512) {                             // Wqb[j][c] = Wq[c][j], j<768
        int bi = blk - 320; int c0 = (bi & 7) * 32, j0 = (bi >> 3) * 32;
        int tx = tid & 31, ty = tid >> 5;
#pragma unroll
        for (int i = 0; i < 4; ++i) ts[ty + i * 8][tx] = Wq[(size_t)(c0 + ty + i * 8) * 1024 + j0 + tx];
        __syncthreads();
#pragma unroll
        for (int i = 0; i < 4; ++i) Wqb[(size_t)(j0 + ty + i * 8) * 256 + c0 + tx] = f2bf(ts[tx][ty + i * 8]);
    } else if (blk < 768) {                             // WvT[c][he] = Wq[c][512+he]
        int c = blk - 512;
        WvT[(size_t)c * 256 + tid] = f2bf(Wq[(size_t)c * 1024 + 512 + tid]);
    } else if (blk < 1280) {                            // XT / XB
        int idx = blk - 768;
        int n0 = (idx & 63) * 64, c0 = ((idx >> 6) & 3) * 64, b = idx >> 8;
        int tn = tid & 63, tc4 = tid >> 6;
        const float* Xb = X + (size_t)b * CN;
        u16* XBb = XB + (size_t)b * CN;
#pragma unroll
        for (int i = 0; i < 16; ++i) {
            int c = c0 + tc4 + i * 4;
            float v = Xb[(size_t)c * N_ + n0 + tn];
            t64[tc4 + i * 4][tn] = v;
            XBb[(size_t)c * N_ + n0 + tn] = f2bf(v);
        }
        __syncthreads();
        u16* Xo = XT + (size_t)b * N_ * C_;
#pragma unroll
        for (int i = 0; i < 16; ++i)
            Xo[(size_t)(n0 + tc4 + i * 4) * C_ + c0 + tn] = f2bf(t64[tn][tc4 + i * 4]);
    } else if (blk < 7112) {                            // zero ATTp
        APz[(size_t)(blk - 1280) * 256 + tid] = 0;
    } else {                                            // zero NRM (1024 fp32)
        ((float4*)NRM)[tid] = make_float4(0.f, 0.f, 0.f, 0.f);
    }
}

// ================ Gram partials: GP[s][b][c][c'] = sum_{n in 256-slice s} x[c][n] x[c'][n] ==========
__global__ __launch_bounds__(256) void k_gram(const u16* __restrict__ XB, float* __restrict__ GP) {
    __shared__ __align__(16) u16 As[2][8192], Bs[2][8192];
    int mt = blockIdx.x & 1, nt = blockIdx.x >> 1, s = blockIdx.y, b = blockIdx.z;
    int c0 = mt * 128, c0p = nt * 128, k0 = s * 256;
    int tid = threadIdx.x, lane = tid & 63, w = tid >> 6;
    int wm = w & 1, wn = w >> 1, qm = lane >> 4, lm = lane & 15;
    int srow = lane >> 3;
    int sperm = (((lane & 7) ^ srow) << 3);
    const u16* aB = XB + ((size_t)(b * 256 + c0 + w * 32 + srow)) * 4096 + k0 + sperm;
    const u16* bB = XB + ((size_t)(b * 256 + c0p + w * 32 + srow)) * 4096 + k0 + sperm;
    int rdp = ((lm & 7) << 3);
    f32x4 acc[4][4] = {};
    auto stg = [&](int p, int kt) {
#pragma unroll
        for (int i = 0; i < 4; ++i) {
            gld16(aB + (size_t)i * 32768 + kt * 64, &As[p][w * 2048 + i * 512]);
            gld16(bB + (size_t)i * 32768 + kt * 64, &Bs[p][w * 2048 + i * 512]);
        }
    };
    stg(0, 0);
#pragma unroll
    for (int kt = 0; kt < 4; ++kt) {
        int p = kt & 1;
        __syncthreads();
        if (kt < 3) stg(p ^ 1, kt + 1);
#pragma unroll
        for (int c2 = 0; c2 < 2; ++c2) {
            frag16 af[4], bf[4];
#pragma unroll
            for (int i = 0; i < 4; ++i)
                af[i] = *(const frag16*)&As[p][(wm * 64 + i * 16 + lm) * 64 + ((((c2 * 4 + qm) << 3) ^ rdp))];
#pragma unroll
            for (int j = 0; j < 4; ++j)
                bf[j] = *(const frag16*)&Bs[p][(wn * 64 + j * 16 + lm) * 64 + ((((c2 * 4 + qm) << 3) ^ rdp))];
#pragma unroll
            for (int i = 0; i < 4; ++i)
#pragma unroll
                for (int j = 0; j < 4; ++j)
                    acc[i][j] = __builtin_amdgcn_mfma_f32_16x16x32_bf16(af[i], bf[j], acc[i][j], 0, 0, 0);
        }
    }
    float* o = GP + (((size_t)s * B_ + b) * 256 + c0 + wm * 64) * 256 + c0p + wn * 64;
#pragma unroll
    for (int i = 0; i < 4; ++i)
#pragma unroll
        for (int j = 0; j < 4; ++j)
#pragma unroll
            for (int r = 0; r < 4; ++r)
                o[(size_t)(i * 16 + qm * 4 + r) * 256 + j * 16 + lm] = acc[i][j][r];
}

// ================ NQ/NK + norm partials ================
__global__ __launch_bounds__(256) void k_nqk(const float* __restrict__ GP, const u16* __restrict__ Wqb,
                                             u16* __restrict__ NQK, float* __restrict__ NRM) {
    __shared__ float Gs[16][260];
    int ct = blockIdx.x, h = blockIdx.y, b = blockIdx.z, t = threadIdx.x;
#pragma unroll
    for (int i = 0; i < 16; ++i) {
        float v = 0.f;
#pragma unroll
        for (int s = 0; s < 16; ++s)
            v += GP[(((size_t)s * B_ + b) * 256 + ct * 16 + i) * 256 + t];
        Gs[i][t] = v;
    }
    __syncthreads();
    int o = t >> 3, cg = t & 7;
    int cl0 = cg * 2, cl1 = cg * 2 + 1;
    const u16* Wk = Wqb + (size_t)(256 + h * 32 + o) * 256;
    const u16* Wqr = Wqb + (size_t)(h * 32 + o) * 256;
    float ak0 = 0.f, ak1 = 0.f, aq0 = 0.f, aq1 = 0.f;
    for (int cp = 0; cp < 256; cp += 8) {
        uint4 kv = *(const uint4*)(Wk + cp);
        uint4 qv = *(const uint4*)(Wqr + cp);
        const u16 *kh = (const u16*)&kv, *qh = (const u16*)&qv;
#pragma unroll
        for (int j = 0; j < 8; ++j) {
            float kf = bb(kh[j]), qf = bb(qh[j]);
            float g0 = Gs[cl0][cp + j], g1v = Gs[cl1][cp + j];
            ak0 += kf * g0; ak1 += kf * g1v;
            aq0 += qf * g0; aq1 += qf * g1v;
        }
    }
    size_t base_q = (((size_t)(b * NH + h) * 2 + 0) * 32 + o) * 256 + ct * 16 + cg * 2;
    *(u32*)(NQK + base_q)        = (u32)f2bf(aq0) | ((u32)f2bf(aq1) << 16);
    *(u32*)(NQK + base_q + 8192) = (u32)f2bf(ak0) | ((u32)f2bf(ak1) << 16);
    u32 wq = *(const u32*)(Wqr + ct * 16 + cg * 2);
    u32 wk = *(const u32*)(Wk + ct * 16 + cg * 2);
    float pq = bb((u16)wq) * aq0 + bb((u16)(wq >> 16)) * aq1;
    float pk = bb((u16)wk) * ak0 + bb((u16)(wk >> 16)) * ak1;
    pq += __shfl_xor(pq, 1); pq += __shfl_xor(pq, 2); pq += __shfl_xor(pq, 4);
    pk += __shfl_xor(pk, 1); pk += __shfl_xor(pk, 2); pk += __shfl_xor(pk, 4);
    if (cg == 0) {
        atomicAdd(&NRM[b * 512 + h * 64 + o], pq);
        atomicAdd(&NRM[b * 512 + h * 64 + 32 + o], pk);
    }
}

// ================ scores (MFMA) + softmax + W_eff strip ================
__global__ __launch_bounds__(256) void k_soft(const u16* __restrict__ NQK, const u16* __restrict__ Wqb,
                                              const u16* __restrict__ WvT, const float* __restrict__ NRM,
                                              u16* __restrict__ MT) {
    __shared__ __align__(16) u16 Ws[8192], Ns[8192];
    __shared__ float Sm[32][33];
    __shared__ float Ab[32][33];
    __shared__ float iqS[32], ikS[32];
    int h = blockIdx.x, b = blockIdx.y;
    int tid = threadIdx.x, lane = tid & 63, w = tid >> 6;
    int wm = w & 1, wn = w >> 1, qm = lane >> 4, lm = lane & 15;
    const u16* Wq = Wqb + ((size_t)h * 32) * 256;
    const u16* NK = NQK + (((size_t)(b * NH + h) * 2 + 1) * 32) * 256;
#pragma unroll
    for (int rp = 0; rp < 4; ++rp) {
        int row = rp * 8 + w * 2 + (lane >> 5);
        int cg = (lane & 31) ^ (row & 31);
        gld16(Wq + (size_t)row * 256 + cg * 8, &Ws[rp * 2048 + w * 512]);
        gld16(NK + (size_t)row * 256 + cg * 8, &Ns[rp * 2048 + w * 512]);
    }
    if (tid < 32) {
        iqS[tid] = 1.0f / fmaxf(sqrtf(fmaxf(NRM[b * 512 + h * 64 + tid], 0.f)), 1e-12f);
        ikS[tid] = 1.0f / fmaxf(sqrtf(fmaxf(NRM[b * 512 + h * 64 + 32 + tid], 0.f)), 1e-12f);
    }
    __syncthreads();
    f32x4 acc = {};
    int rowA = wm * 16 + lm, rowB = wn * 16 + lm;
#pragma unroll
    for (int kk = 0; kk < 8; ++kk) {
        int sA = ((kk * 4 + qm) ^ (rowA & 31)) << 3;
        int sB = ((kk * 4 + qm) ^ (rowB & 31)) << 3;
        frag16 af = *(const frag16*)&Ws[rowA * 256 + sA];
        frag16 bf = *(const frag16*)&Ns[rowB * 256 + sB];
        acc = __builtin_amdgcn_mfma_f32_16x16x32_bf16(af, bf, acc, 0, 0, 0);
    }
#pragma unroll
    for (int r = 0; r < 4; ++r) Sm[wm * 16 + qm * 4 + r][wn * 16 + lm] = acc[r];
    __syncthreads();
    if (tid < 32) {
        float iq = iqS[tid];
        float sv[32], m = -1e30f;
#pragma unroll
        for (int e = 0; e < 32; ++e) { sv[e] = Sm[tid][e] * iq * ikS[e]; m = fmaxf(m, sv[e]); }
        float sm = 0.f;
#pragma unroll
        for (int e = 0; e < 32; ++e) { sv[e] = __expf(sv[e] - m); sm += sv[e]; }
        float rin = 1.0f / sm;
#pragma unroll
        for (int e = 0; e < 32; ++e) Ab[tid][e] = sv[e] * rin;
    }
    __syncthreads();
    frag16 bf2[2];
#pragma unroll
    for (int j = 0; j < 2; ++j) {
        __align__(16) u16 tmp[8];
#pragma unroll
        for (int ii = 0; ii < 8; ++ii) tmp[ii] = f2bf(Ab[j * 16 + lm][qm * 8 + ii]);
        bf2[j] = *(const frag16*)tmp;
    }
    f32x4 acc2[4][2] = {};
#pragma unroll
    for (int i = 0; i < 4; ++i) {
        int row = w * 64 + i * 16 + lm;
        frag16 af = *(const frag16*)&WvT[(size_t)row * 256 + h * 32 + qm * 8];
#pragma unroll
        for (int j = 0; j < 2; ++j)
            acc2[i][j] = __builtin_amdgcn_mfma_f32_16x16x32_bf16(af, bf2[j], acc2[i][j], 0, 0, 0);
    }
    u16* Mo = MT + (size_t)b * 65536;
#pragma unroll
    for (int i = 0; i < 4; ++i)
#pragma unroll
        for (int j = 0; j < 2; ++j)
#pragma unroll
            for (int r = 0; r < 4; ++r)
                Mo[(size_t)(w * 64 + i * 16 + qm * 4 + r) * 256 + h * 32 + j * 16 + lm] = f2bf(acc2[i][j][r]);
}

// ================ Wfull[c][c''] = g1[c] * sum_j W2B[c][j] * MT[c''][j] ================
__global__ __launch_bounds__(256) void k_wfull(const u16* __restrict__ W2B, const u16* __restrict__ MT,
                                               const float* __restrict__ g1, u16* __restrict__ WFU) {
    __shared__ __align__(16) u16 As[2][8192], Bs[2][8192];
    int c0 = blockIdx.x * 128, cq0 = blockIdx.y * 128, b = blockIdx.z;
    int tid = threadIdx.x, lane = tid & 63, w = tid >> 6;
    int wm = w & 1, wn = w >> 1, qm = lane >> 4, lm = lane & 15;
    int srow = lane >> 3;
    int sperm = (((lane & 7) ^ srow) << 3);
    const u16* aB = W2B + ((size_t)(c0 + w * 32 + srow)) * 256 + sperm;
    const u16* bB = MT + ((size_t)(b * 256 + cq0 + w * 32 + srow)) * 256 + sperm;
    int rdp = ((lm & 7) << 3);
    f32x4 acc[4][4] = {};
    auto stg = [&](int p, int kc) {
#pragma unroll
        for (int i = 0; i < 4; ++i) {
            gld16(aB + i * 2048 + kc * 64, &As[p][w * 2048 + i * 512]);
            gld16(bB + i * 2048 + kc * 64, &Bs[p][w * 2048 + i * 512]);
        }
    };
    stg(0, 0);
#pragma unroll
    for (int kt = 0; kt < 4; ++kt) {
        int p = kt & 1;
        __syncthreads();
        if (kt < 3) stg(p ^ 1, kt + 1);
#pragma unroll
        for (int c2 = 0; c2 < 2; ++c2) {
            frag16 af[4], bf[4];
#pragma unroll
            for (int i = 0; i < 4; ++i)
                af[i] = *(const frag16*)&As[p][(wm * 64 + i * 16 + lm) * 64 + ((((c2 * 4 + qm) << 3) ^ rdp))];
#pragma unroll
            for (int j = 0; j < 4; ++j)
                bf[j] = *(const frag16*)&Bs[p][(wn * 64 + j * 16 + lm) * 64 + ((((c2 * 4 + qm) << 3) ^ rdp))];
#pragma unroll
            for (int i = 0; i < 4; ++i)
#pragma unroll
                for (int j = 0; j < 4; ++j)
                    acc[i][j] = __builtin_amdgcn_mfma_f32_16x16x32_bf16(af[i], bf[j], acc[i][j], 0, 0, 0);
        }
    }
#pragma unroll
    for (int i = 0; i < 4; ++i)
#pragma unroll
        for (int r = 0; r < 4; ++r) {
            int c = c0 + wm * 64 + i * 16 + qm * 4 + r;
            float gv = g1[c];
#pragma unroll
            for (int j = 0; j < 4; ++j) {
                int cc = cq0 + wn * 64 + j * 16 + lm;
                WFU[((size_t)b * 256 + c) * 256 + cc] = f2bf(gv * acc[i][j][r]);
            }
        }
}

// ================ att GEMM 128c x 64n: ATT = x + Wfull @ x + g1*b2 -> ATTb, ATTp ================
__global__ __launch_bounds__(256) void k_att(const u16* __restrict__ WFU, const u16* __restrict__ XT,
                                             const float* __restrict__ bias2, const float* __restrict__ g1,
                                             const float* __restrict__ X, u16* __restrict__ ATTb,
                                             u16* __restrict__ ATTp) {
    __shared__ __align__(16) u16 As[2][8192], Bs[2][4096];
    int n0 = blockIdx.x * 64, c0 = blockIdx.y * 128, b = blockIdx.z;
    int tid = threadIdx.x, lane = tid & 63, w = tid >> 6;
    int wm = w & 1, wn = w >> 1, qm = lane >> 4, lm = lane & 15;
    int srow = lane >> 3;
    int sperm = (((lane & 7) ^ srow) << 3);
    const u16* aB = WFU + ((size_t)(b * 256 + c0 + w * 32 + srow)) * 256 + sperm;
    const u16* bB = XT + ((size_t)b * N_) * 256 + sperm;
    int bRow[2];
#pragma unroll
    for (int i = 0; i < 2; ++i) bRow[i] = (n0 + w * 16 + i * 8 + srow) * 256;
    int rdp = ((lm & 7) << 3);
    f32x4 acc[4][2] = {};
    auto stg = [&](int p, int kc) {
#pragma unroll
        for (int i = 0; i < 4; ++i)
            gld16(aB + i * 2048 + kc * 64, &As[p][w * 2048 + i * 512]);
#pragma unroll
        for (int i = 0; i < 2; ++i)
            gld16(bB + bRow[i] + kc * 64, &Bs[p][w * 1024 + i * 512]);
    };
    stg(0, 0);
#pragma unroll
    for (int kt = 0; kt < 4; ++kt) {
        int p = kt & 1;
        __syncthreads();
        if (kt < 3) stg(p ^ 1, kt + 1);
#pragma unroll
        for (int c2 = 0; c2 < 2; ++c2) {
            frag16 af[4], bf[2];
#pragma unroll
            for (int i = 0; i < 4; ++i)
                af[i] = *(const frag16*)&As[p][(wm * 64 + i * 16 + lm) * 64 + ((((c2 * 4 + qm) << 3) ^ rdp))];
#pragma unroll
            for (int j = 0; j < 2; ++j)
                bf[j] = *(const frag16*)&Bs[p][(wn * 32 + j * 16 + lm) * 64 + ((((c2 * 4 + qm) << 3) ^ rdp))];
#pragma unroll
            for (int i = 0; i < 4; ++i)
#pragma unroll
                for (int j = 0; j < 2; ++j)
                    acc[i][j] = __builtin_amdgcn_mfma_f32_16x16x32_bf16(af[i], bf[j], acc[i][j], 0, 0, 0);
        }
    }
    int c_base = c0 + wm * 64, n_base = n0 + wn * 32;
    const float* xin = X + (size_t)b * CN;
    u16* Ao = ATTb + (size_t)b * CN;
    u16* Ap = ATTp + ((size_t)b * PADV << 8);
    float val[4][2][4];
#pragma unroll
    for (int i = 0; i < 4; ++i)
#pragma unroll
        for (int r = 0; r < 4; ++r) {
            int c = c_base + i * 16 + qm * 4 + r;
            float gb2 = g1[c] * bias2[c];
#pragma unroll
            for (int j = 0; j < 2; ++j) {
                int n = n_base + j * 16 + lm;
                float v = xin[(size_t)c * N_ + n] + acc[i][j][r] + gb2;
                val[i][j][r] = v;
                Ao[(size_t)c * N_ + n] = f2bf(v);
            }
        }
#pragma unroll
    for (int j = 0; j < 2; ++j) {
        int n = n_base + j * 16 + lm;
        int pr = padrow(n);
#pragma unroll
        for (int i = 0; i < 4; ++i) {
            ushort4 pk;
            pk.x = f2bf(val[i][j][0]); pk.y = f2bf(val[i][j][1]);
            pk.z = f2bf(val[i][j][2]); pk.w = f2bf(val[i][j][3]);
            *(ushort4*)&Ap[((size_t)pr << 8) + c_base + i * 16 + qm * 4] = pk;
        }
    }
}

// ================ conv 3^3 MFMA (r10 proven): 128co x 64n, split-K=3, LDS dbuf A+B ================
__global__ __launch_bounds__(256) void k_conv_mfma(const u16* __restrict__ WT2, const u16* __restrict__ ATTp,
                                                   u16* __restrict__ Pk) {
    __shared__ __align__(16) u16 As[2][8192], Bs[2][4096];
    int n0 = blockIdx.x * 64;
    int co0 = (blockIdx.y & 1) * 128, ks = blockIdx.y >> 1;
    int b = blockIdx.z;
    int tid = threadIdx.x, lane = tid & 63, w = tid >> 6;
    int wm = w & 1, wn = w >> 1, qm = lane >> 4, lm = lane & 15;
    int srow = lane >> 3;
    int sperm = (((lane & 7) ^ srow) << 3);
    const u16* aB = WT2 + (((size_t)ks * 9 * 256 + co0 + w * 32 + srow) << 8) + sperm;
    int prA[2];
#pragma unroll
    for (int i = 0; i < 2; ++i) prA[i] = padrow(n0 + w * 16 + i * 8 + srow) << 8;
    const u16* bB = ATTp + ((size_t)b * PADV << 8) + ((ks - 1) * 324 << 8) + sperm;
    int rdp = ((lm & 7) << 3);
    f32x4 acc[4][2] = {};
    auto stg = [&](int p, int kt) {
        int tap9 = kt >> 2, kc = kt & 3;
        int K9 = ((tap9 / 3) - 1) * 18 + (tap9 % 3 - 1);   // constant-folds under full unroll
#pragma unroll
        for (int i = 0; i < 4; ++i)
            gld16(aB + (size_t)tap9 * 65536 + i * 2048 + kc * 64, &As[p][w * 2048 + i * 512]);
#pragma unroll
        for (int i = 0; i < 2; ++i)
            gld16(bB + prA[i] + K9 * 256 + kc * 64, &Bs[p][w * 1024 + i * 512]);
    };
    stg(0, 0);
#pragma unroll
    for (int kt = 0; kt < 36; ++kt) {
        int p = kt & 1;
        __syncthreads();
        if (kt < 35) stg(p ^ 1, kt + 1);
#pragma unroll
        for (int c2 = 0; c2 < 2; ++c2) {
            frag16 af[4], bf[2];
#pragma unroll
            for (int i = 0; i < 4; ++i)
                af[i] = *(const frag16*)&As[p][(wm * 64 + i * 16 + lm) * 64 + ((((c2 * 4 + qm) << 3) ^ rdp))];
#pragma unroll
            for (int j = 0; j < 2; ++j)
                bf[j] = *(const frag16*)&Bs[p][(wn * 32 + j * 16 + lm) * 64 + ((((c2 * 4 + qm) << 3) ^ rdp))];
#pragma unroll
            for (int i = 0; i < 4; ++i)
#pragma unroll
                for (int j = 0; j < 2; ++j)
                    acc[i][j] = __builtin_amdgcn_mfma_f32_16x16x32_bf16(af[i], bf[j], acc[i][j], 0, 0, 0);
        }
    }
    u16* Pb = Pk + ((size_t)(ks * B_ + b) * C_ + co0 + wm * 64) * N_ + n0 + wn * 32;
#pragma unroll
    for (int i = 0; i < 4; ++i)
#pragma unroll
        for (int j = 0; j < 2; ++j)
#pragma unroll
            for (int r = 0; r < 4; ++r)
                Pb[(size_t)(i * 16 + qm * 4 + r) * N_ + j * 16 + lm] = f2bf(acc[i][j][r]);
}

// ================ combine bf16 split-K -> bf16 Y + batch mean/var partials ================
__global__ __launch_bounds__(256) void k_gn_reduce(const u16* __restrict__ Pk, u16* __restrict__ Y,
                                                   float* __restrict__ RED) {
    int blk = blockIdx.x, b = blockIdx.y;
    size_t base = (size_t)b * CN + (size_t)blk * 16384;
    const u16* p0 = Pk + base;
    const u16* p1 = Pk + BCN + base;
    const u16* p2 = Pk + (size_t)2 * BCN + base;
    u16* y = Y + base;
    float s = 0.f, q = 0.f;
    for (int u = threadIdx.x * 8; u < 16384; u += 2048) {
        uint4 a = *(const uint4*)&p0[u];
        uint4 c1 = *(const uint4*)&p1[u];
        uint4 c2 = *(const uint4*)&p2[u];
        const u16 *A = (const u16*)&a, *B1 = (const u16*)&c1, *C2 = (const u16*)&c2;
        __align__(16) u16 outp[8];
#pragma unroll
        for (int i = 0; i < 8; ++i) {
            float v = bb(A[i]) + bb(B1[i]) + bb(C2[i]);
            s += v; q += v * v;
            outp[i] = f2bf(v);
        }
        *(uint4*)&y[u] = *(const uint4*)outp;
    }
#pragma unroll
    for (int off = 32; off; off >>= 1) { s += __shfl_down(s, off); q += __shfl_down(q, off); }
    __shared__ float rs_[4], rq[4];
    int lane = threadIdx.x & 63, wv = threadIdx.x >> 6;
    if (!lane) { rs_[wv] = s; rq[wv] = q; }
    __syncthreads();
    if (threadIdx.x == 0) {
        RED[((size_t)b * 64 + blk) * 2 + 0] = rs_[0] + rs_[1] + rs_[2] + rs_[3];
        RED[((size_t)b * 64 + blk) * 2 + 1] = rq[0] + rq[1] + rq[2] + rq[3];
    }
}

// ================ finalize ================
__global__ __launch_bounds__(256) void k_final(const u16* __restrict__ Y, const u16* __restrict__ ATTb,
                                               const float* __restrict__ RED, const float* __restrict__ gw,
                                               const float* __restrict__ gb, float* __restrict__ out) {
    int i = blockIdx.x * 256 + threadIdx.x;
    int b = i >> 20;
    int c = (i >> 12) & 255;
    __shared__ float smu[2];
    if (threadIdx.x < 64) {
        float s = RED[((size_t)b * 64 + threadIdx.x) * 2 + 0];
        float q = RED[((size_t)b * 64 + threadIdx.x) * 2 + 1];
#pragma unroll
        for (int off = 32; off; off >>= 1) { s += __shfl_down(s, off); q += __shfl_down(q, off); }
        if (threadIdx.x == 0) {
            float inv = 1.0f / (float)CN;
            float mu = s * inv, var = q * inv - mu * mu;
            smu[0] = mu; smu[1] = rsqrtf(var + 1e-5f);
        }
    }
    __syncthreads();
    float v = (bb(Y[i]) - smu[0]) * smu[1] * gw[c] + gb[c] + bb(ATTb[i]);
    out[i] = v >= 0.f ? v : 0.01f * v;
}

extern "C" void kernel_launch(void* const* d_in, const int* in_sizes, int n_in,
                              void* d_out, int out_size, void* d_ws, size_t ws_size,
                              hipStream_t stream) {
    const float* x      = (const float*)d_in[0];
    const float* Wqkvv  = (const float*)d_in[1];
    // d_in[2] W_out, d_in[3] b_out, d_in[10] index_sample: DEAD in reference
    const float* W_out2 = (const float*)d_in[4];
    const float* b_out2 = (const float*)d_in[5];
    const float* gamma1 = (const float*)d_in[6];
    const float* conv_w = (const float*)d_in[7];
    const float* gn_w   = (const float*)d_in[8];
    const float* gn_b   = (const float*)d_in[9];
    float* out = (float*)d_out;
    float* ws = (float*)d_ws;

    u16*   XB   = (u16*)(ws + OFF_XB16);
    float* GP   = ws + OFF_GP;
    u16*   NQK  = (u16*)(ws + OFF_NQK);
    u16*   Pk   = (u16*)(ws + OFF_PK);    // aliases XB+GP (dead before conv)
    u16*   Y    = (u16*)(ws + OFF_Y);     // aliases NQK (dead before gn_reduce)
    u16*   ATTb = (u16*)(ws + OFF_ATTB);
    u16*   ATTp = (u16*)(ws + OFF_ATTP);
    u16*   WT2  = (u16*)(ws + OFF_WT2);
    u16*   W2B  = (u16*)(ws + OFF_W2B);
    u16*   Wqb  = (u16*)(ws + OFF_WQB);
    u16*   XT   = (u16*)(ws + OFF_XT);
    u16*   WvT  = (u16*)(ws + OFF_WVT);
    u16*   MT   = (u16*)(ws + OFF_MT);
    u16*   WFU  = (u16*)(ws + OFF_WFU);
    float* NRM  = ws + OFF_NRM;
    float* RED  = ws + OFF_RED;

    k_prep      <<<7113, 256, 0, stream>>>(conv_w, W_out2, Wqkvv, x, WT2, W2B, Wqb, WvT, XT, XB, (u32*)ATTp, NRM);
    k_gram      <<<dim3(4, 16, B_), 256, 0, stream>>>(XB, GP);
    k_nqk       <<<dim3(16, NH, B_), 256, 0, stream>>>(GP, Wqb, NQK, NRM);
    k_soft      <<<dim3(NH, B_), 256, 0, stream>>>(NQK, Wqb, WvT, NRM, MT);
    k_wfull     <<<dim3(2, 2, B_), 256, 0, stream>>>(W2B, MT, gamma1, WFU);
    k_att       <<<dim3(64, 2, B_), 256, 0, stream>>>(WFU, XT, b_out2, gamma1, x, ATTb, ATTp);
    k_conv_mfma <<<dim3(64, 6, B_), 256, 0, stream>>>(WT2, ATTp, Pk);
    k_gn_reduce <<<dim3(64, B_), 256, 0, stream>>>(Pk, Y, RED);
    k_final     <<<8192, 256, 0, stream>>>(Y, ATTb, RED, gn_w, gn_b, out);
}